// Round 8
// baseline (348.107 us; speedup 1.0000x reference)
//
#include <hip/hip_runtime.h>
#include <hip/hip_bf16.h>
#include <math.h>

#define NN 4096
#define MM 1024
#define BANDP 512

typedef float f4v __attribute__((ext_vector_type(4)));
typedef float f32x4 __attribute__((ext_vector_type(4)));
typedef short bf16x8 __attribute__((ext_vector_type(8)));
typedef short s4v __attribute__((ext_vector_type(4)));
typedef unsigned int u4v __attribute__((ext_vector_type(4)));

__device__ __forceinline__ short f2b(float f) {
    union { float f; unsigned u; } v; v.f = f;
    unsigned r = v.u + 0x7fffu + ((v.u >> 16) & 1u);
    return (short)(r >> 16);
}
__device__ __forceinline__ float b2f(short s) {
    union { unsigned u; float f; } v;
    v.u = ((unsigned)(unsigned short)s) << 16;
    return v.f;
}
__device__ __forceinline__ float b2f_lo(unsigned p) {
    union { unsigned u; float f; } v; v.u = p << 16; return v.f;
}
__device__ __forceinline__ float b2f_hi(unsigned p) {
    union { unsigned u; float f; } v; v.u = p & 0xffff0000u; return v.f;
}

__device__ __forceinline__ void gl2lds16(const void* g, void* l) {
    __builtin_amdgcn_global_load_lds(
        (const __attribute__((address_space(1))) void*)g,
        (__attribute__((address_space(3))) void*)l, 16, 0, 0);
}

#define WAIT_VM8() asm volatile("s_waitcnt vmcnt(8)" ::: "memory")
#define WAIT_VM4() asm volatile("s_waitcnt vmcnt(4)" ::: "memory")
#define WAIT_VM0() asm volatile("s_waitcnt vmcnt(0)" ::: "memory")

// ---------------- x (fp32) -> bf16 hi/lo split ------------------------------
__global__ __launch_bounds__(256)
void split_x_k(const float* __restrict__ s, short* __restrict__ h,
               short* __restrict__ l)
{
    const int i = (blockIdx.x * 256 + threadIdx.x) << 2;
    f4v v = *(const f4v*)&s[i];
    s4v hv, lv;
    #pragma unroll
    for (int q = 0; q < 4; ++q) {
        hv[q] = f2b(v[q]);
        lv[q] = f2b(v[q] - b2f(hv[q]));
    }
    *(s4v*)&h[i] = hv;
    *(s4v*)&l[i] = lv;
}

// ---------------- build horizontal-pair gather table (16 MB!) ---------------
// pairs[i][j] = bf16(x[i][j]) | bf16(x[i][min(j+1,1023)])<<16
__global__ __launch_bounds__(256)
void build_pairs_k(const float* __restrict__ x, unsigned* __restrict__ pairs)
{
    const int i = blockIdx.x;
    const int t = threadIdx.x;
    const int j4 = t << 2;
    const float* row = x + (size_t)i * MM;
    f4v v = *(const f4v*)&row[j4];
    const float nb = (j4 + 4 < MM) ? row[j4 + 4] : row[MM - 1];
    u4v o;
    #pragma unroll
    for (int q = 0; q < 4; ++q) {
        const float a = v[q];
        const float b = (q < 3) ? v[q + 1] : ((j4 + 4 < MM) ? nb : a);
        o[q] = (unsigned)(unsigned short)f2b(a)
             | ((unsigned)(unsigned short)f2b(b) << 16);
    }
    *(u4v*)&pairs[(size_t)i * MM + j4] = o;
}

// ---------------- fp32 weight -> transposed bf16 hi/lo ----------------------
__global__ __launch_bounds__(256)
void trsplit_k(const float* __restrict__ W, short* __restrict__ Th,
               short* __restrict__ Tl)
{
    __shared__ float tile[32][33];
    const int bx = blockIdx.x << 5, by = blockIdx.y << 5;
    const int tx = threadIdx.x, ty = threadIdx.y;
    #pragma unroll
    for (int r = ty; r < 32; r += 8)
        tile[r][tx] = W[(size_t)(by + r) * MM + bx + tx];
    __syncthreads();
    #pragma unroll
    for (int r = ty; r < 32; r += 8) {
        const float v = tile[tx][r];
        const short h = f2b(v);
        Th[(size_t)(bx + r) * MM + by + tx] = h;
        Tl[(size_t)(bx + r) * MM + by + tx] = f2b(v - b2f(h));
    }
}

// ---------------- fp32 weight -> transposed bf16 (single) -------------------
__global__ __launch_bounds__(256)
void transpose_f32_bf16(const float* __restrict__ W, short* __restrict__ Wt)
{
    __shared__ float tile[32][33];
    const int bx = blockIdx.x << 5, by = blockIdx.y << 5;
    const int tx = threadIdx.x, ty = threadIdx.y;
    #pragma unroll
    for (int r = ty; r < 32; r += 8)
        tile[r][tx] = W[(size_t)(by + r) * MM + bx + tx];
    __syncthreads();
    #pragma unroll
    for (int r = ty; r < 32; r += 8)
        Wt[(size_t)(bx + r) * MM + by + tx] = f2b(tile[tx][r]);
}

// ---------------- split-bf16 3-term MFMA GEMM (fp32-faithful path) ----------
template<bool BIAS>
__global__ __launch_bounds__(256, 2)
void gemm_split(const short* __restrict__ Ah, const short* __restrict__ Al,
                const short* __restrict__ Bth, const short* __restrict__ Btl,
                const float* __restrict__ bias0, const float* __restrict__ bias1,
                short* __restrict__ outH, short* __restrict__ outL, int N)
{
    __shared__ short As[2][2][128 * 32];
    __shared__ short Bs[2][2][128 * 32];

    const int t  = threadIdx.x;
    const int l  = t & 63;
    const int w  = t >> 6;
    const int wm = w >> 1, wn = w & 1;
    const int lr = l & 15;
    const int lk = (l >> 4) << 3;
    const int lks = lk ^ (((l >> 1) & 3) << 3);   // swizzled read col (elems)

    const int i0 = blockIdx.y << 7;
    const int bn = blockIdx.x << 7;

    const int sr = t >> 2;
    const int sk = (((t & 3) ^ ((t >> 3) & 3)) << 3);  // inverse-swz source col

    const short* aH = Ah  + (size_t)(i0 + sr) * MM + sk;
    const short* aL = Al  + (size_t)(i0 + sr) * MM + sk;
    const short* bH = Bth + (size_t)(bn + sr) * MM + sk;
    const short* bL = Btl + (size_t)(bn + sr) * MM + sk;

    f32x4 acc[4][4] = {};

    auto stage = [&](int sb, int k0) {
        gl2lds16(aH + k0,           &As[sb][0][t * 8]);
        gl2lds16(aH + 64 * MM + k0, &As[sb][0][2048 + t * 8]);
        gl2lds16(aL + k0,           &As[sb][1][t * 8]);
        gl2lds16(aL + 64 * MM + k0, &As[sb][1][2048 + t * 8]);
        gl2lds16(bH + k0,           &Bs[sb][0][t * 8]);
        gl2lds16(bH + 64 * MM + k0, &Bs[sb][0][2048 + t * 8]);
        gl2lds16(bL + k0,           &Bs[sb][1][t * 8]);
        gl2lds16(bL + 64 * MM + k0, &Bs[sb][1][2048 + t * 8]);
    };
    stage(0, 0);

    for (int kt = 0; kt < 32; ++kt) {
        const int cur = kt & 1;
        if (kt + 1 < 32) { stage(cur ^ 1, (kt + 1) << 5); WAIT_VM8(); }
        else             { WAIT_VM0(); }
        __builtin_amdgcn_s_barrier();
        __builtin_amdgcn_sched_barrier(0);

        bf16x8 ah[4], al[4], bh[4], bl[4];
        #pragma unroll
        for (int i = 0; i < 4; ++i) {
            ah[i] = *(const bf16x8*)&As[cur][0][(wm * 64 + i * 16 + lr) * 32 + lks];
            al[i] = *(const bf16x8*)&As[cur][1][(wm * 64 + i * 16 + lr) * 32 + lks];
        }
        #pragma unroll
        for (int j = 0; j < 4; ++j) {
            bh[j] = *(const bf16x8*)&Bs[cur][0][(wn * 64 + j * 16 + lr) * 32 + lks];
            bl[j] = *(const bf16x8*)&Bs[cur][1][(wn * 64 + j * 16 + lr) * 32 + lks];
        }
        __builtin_amdgcn_s_setprio(1);
        #pragma unroll
        for (int i = 0; i < 4; ++i)
            #pragma unroll
            for (int j = 0; j < 4; ++j) {
                acc[i][j] = __builtin_amdgcn_mfma_f32_16x16x32_bf16(ah[i], bl[j], acc[i][j], 0, 0, 0);
                acc[i][j] = __builtin_amdgcn_mfma_f32_16x16x32_bf16(al[i], bh[j], acc[i][j], 0, 0, 0);
                acc[i][j] = __builtin_amdgcn_mfma_f32_16x16x32_bf16(ah[i], bh[j], acc[i][j], 0, 0, 0);
            }
        __builtin_amdgcn_s_setprio(0);
        __builtin_amdgcn_s_barrier();
    }

    const int rb = (l >> 4) << 2;
    #pragma unroll
    for (int i = 0; i < 4; ++i)
        #pragma unroll
        for (int j = 0; j < 4; ++j) {
            const int n = bn + wn * 64 + j * 16 + lr;
            float bv = 0.f;
            if (BIAS) bv = (n < 1024) ? bias0[n] : bias1[n - 1024];
            #pragma unroll
            for (int r = 0; r < 4; ++r) {
                const int m = i0 + wm * 64 + i * 16 + rb + r;
                const float v = acc[i][j][r] + bv;
                const short h = f2b(v);
                outH[(size_t)m * N + n] = h;
                outL[(size_t)m * N + n] = f2b(v - b2f(h));
            }
        }
}

// ---------------- bilinear grid sample from pair table ----------------------
// 2 aligned u32 loads per output (horizontal pair from row iy0 and iy0+1).
__global__ __launch_bounds__(256)
void grid_sample_k(const unsigned* __restrict__ pairs, const short* __restrict__ ofh,
                   const short* __restrict__ ofl, short* __restrict__ xnb)
{
    const int i = blockIdx.x;
    const int tid = threadIdx.x;
    const int j4 = tid << 2;

    const short* rh = ofh + (size_t)i * 2048;
    const short* rl = ofl + (size_t)i * 2048;
    s4v hx = *(const s4v*)&rh[j4];
    s4v lx = *(const s4v*)&rl[j4];
    s4v hy = *(const s4v*)&rh[1024 + j4];
    s4v ly = *(const s4v*)&rl[1024 + j4];
    s4v out;

    const float gxb = (2.0f * (float)i) / (float)NN - 1.0f;

    #pragma unroll
    for (int q = 0; q < 4; ++q) {
        const int j = j4 + q;
        float gx = gxb + b2f(hx[q]) + b2f(lx[q]);
        gx = fminf(fmaxf(gx, -1.0f), 1.0f);
        float gy = (2.0f * (float)j) / (float)MM - 1.0f + b2f(hy[q]) + b2f(ly[q]);
        gy = fminf(fmaxf(gy, -1.0f), 1.0f);

        const float ixf = (gx + 1.0f) * 511.5f;
        const float iyf = (gy + 1.0f) * 2047.5f;
        const float ix0 = floorf(ixf);
        const float iy0 = floorf(iyf);
        const float wx = ixf - ix0;
        const float wy = iyf - iy0;
        int ix0i = (int)ix0; ix0i = max(0, min(ix0i, MM - 1));
        int iy0i = (int)iy0; iy0i = max(0, min(iy0i, NN - 1));
        const int iy1i = min(iy0i + 1, NN - 1);

        const unsigned p0 = pairs[(size_t)iy0i * MM + ix0i];
        const unsigned p1 = pairs[(size_t)iy1i * MM + ix0i];
        const float v00 = b2f_lo(p0), v01 = b2f_hi(p0);
        const float v10 = b2f_lo(p1), v11 = b2f_hi(p1);
        out[q] = f2b((1.0f - wy) * ((1.0f - wx) * v00 + wx * v01)
                   + wy * ((1.0f - wx) * v10 + wx * v11));
    }
    *(s4v*)&xnb[(size_t)i * MM + j4] = out;
}

// ---------------- bf16 MFMA GEMM, A[4096x1024] @ Bt^T -----------------------
// MODE 2: C0 fp32 row-major [4096][1024]
// MODE 3: banded logits -> C0 band fp32 [4096][512] with -inf mask; Bt=K
// MODE 4: fused K|V: n<1024 -> C0 = K bf16 [4096][1024]; else C1 = Vt bf16 [1024][4096]
template<int MODE>
__global__ __launch_bounds__(256, 2)
void mfma_gemm(const short* __restrict__ A, const short* __restrict__ Bt,
               void* __restrict__ C0, void* __restrict__ C1)
{
    __shared__ short As[2][128 * 32];
    __shared__ short Bs[2][128 * 32];

    const int t  = threadIdx.x;
    const int l  = t & 63;
    const int w  = t >> 6;
    const int wm = w >> 1, wn = w & 1;
    const int lr = l & 15;
    const int lk = (l >> 4) << 3;
    const int lks = lk ^ (((l >> 1) & 3) << 3);

    const int i0 = blockIdx.y << 7;
    const int bn = blockIdx.x << 7;
    const int jb = (MODE == 3) ? (i0 - 256 + bn) : bn;

    const int sr = t >> 2;
    const int sk = (((t & 3) ^ ((t >> 3) & 3)) << 3);

    const short* aS = A + (size_t)(i0 + sr) * MM + sk;
    int br0 = jb + sr, br1 = jb + sr + 64;
    if (MODE == 3) {
        br0 = min(max(br0, 0), NN - 1);
        br1 = min(max(br1, 0), NN - 1);
    }
    const short* bS0 = Bt + (size_t)br0 * MM + sk;
    const short* bS1 = Bt + (size_t)br1 * MM + sk;

    f32x4 acc[4][4] = {};

    auto stage = [&](int sb, int k0) {
        gl2lds16(aS + k0,           &As[sb][0] + t * 8);
        gl2lds16(aS + 64 * MM + k0, &As[sb][0] + 2048 + t * 8);
        gl2lds16(bS0 + k0,          &Bs[sb][0] + t * 8);
        gl2lds16(bS1 + k0,          &Bs[sb][0] + 2048 + t * 8);
    };
    stage(0, 0);

    for (int kt = 0; kt < 32; ++kt) {
        const int cur = kt & 1;
        if (kt + 1 < 32) { stage(cur ^ 1, (kt + 1) << 5); WAIT_VM4(); }
        else             { WAIT_VM0(); }
        __builtin_amdgcn_s_barrier();
        __builtin_amdgcn_sched_barrier(0);

        bf16x8 a[4], b[4];
        #pragma unroll
        for (int i = 0; i < 4; ++i)
            a[i] = *(const bf16x8*)&As[cur][(wm * 64 + i * 16 + lr) * 32 + lks];
        #pragma unroll
        for (int j = 0; j < 4; ++j)
            b[j] = *(const bf16x8*)&Bs[cur][(wn * 64 + j * 16 + lr) * 32 + lks];
        __builtin_amdgcn_s_setprio(1);
        #pragma unroll
        for (int i = 0; i < 4; ++i)
            #pragma unroll
            for (int j = 0; j < 4; ++j)
                acc[i][j] = __builtin_amdgcn_mfma_f32_16x16x32_bf16(a[i], b[j], acc[i][j], 0, 0, 0);
        __builtin_amdgcn_s_setprio(0);
        __builtin_amdgcn_s_barrier();
    }

    const int rb = (l >> 4) << 2;
    #pragma unroll
    for (int i = 0; i < 4; ++i) {
        #pragma unroll
        for (int j = 0; j < 4; ++j) {
            const int nl = wn * 64 + j * 16 + lr;
            if (MODE == 4 && bn + nl >= 1024) {
                const int m0 = i0 + wm * 64 + i * 16 + rb;
                s4v o;
                #pragma unroll
                for (int r = 0; r < 4; ++r) o[r] = f2b(acc[i][j][r]);
                *(s4v*)&((short*)C1)[(size_t)(bn + nl - 1024) * NN + m0] = o;
            } else {
                #pragma unroll
                for (int r = 0; r < 4; ++r) {
                    const int m = i0 + wm * 64 + i * 16 + rb + r;
                    const float v = acc[i][j][r];
                    if (MODE == 4) {
                        ((short*)C0)[(size_t)m * MM + bn + nl] = f2b(v);
                    } else if (MODE == 2) {
                        ((float*)C0)[(size_t)m * MM + bn + nl] = v;
                    } else if (MODE == 3) {
                        const int jj = jb + nl;
                        const int ci = jj - m + 255;
                        if (ci >= 0 && ci <= 510)
                            ((float*)C0)[(size_t)m * BANDP + ci] =
                                (jj >= 0 && jj < NN) ? 0.06f * v : -INFINITY;
                    }
                }
            }
        }
    }
}

// ---------------- softmax over band; writes att rows + bandT scatter --------
__global__ __launch_bounds__(256)
void band_softmax(const float* __restrict__ band, float* __restrict__ att,
                  short* __restrict__ bandT)
{
    const int i = blockIdx.x;
    const int tid = threadIdx.x;
    const float* brow = band + (size_t)i * BANDP;

    float v0 = brow[tid];
    float v1 = (tid < 255) ? brow[tid + 256] : -INFINITY;

    float m = fmaxf(v0, v1);
    #pragma unroll
    for (int o = 32; o >= 1; o >>= 1) m = fmaxf(m, __shfl_xor(m, o));
    __shared__ float redm[4], reds[4];
    const int wv = tid >> 6, ln = tid & 63;
    if (ln == 0) redm[wv] = m;
    __syncthreads();
    m = fmaxf(fmaxf(redm[0], redm[1]), fmaxf(redm[2], redm[3]));

    float p0 = expf(v0 - m);
    float p1 = (tid < 255) ? expf(v1 - m) : 0.f;
    float s = p0 + p1;
    #pragma unroll
    for (int o = 32; o >= 1; o >>= 1) s += __shfl_xor(s, o);
    if (ln == 0) reds[wv] = s;
    __syncthreads();
    s = reds[0] + reds[1] + reds[2] + reds[3];
    const float rinv = 1.0f / s;
    p0 *= rinv; p1 *= rinv;

    float* arow = att + (size_t)i * NN;
    f4v z = {0.f, 0.f, 0.f, 0.f};
    #pragma unroll
    for (int q = 0; q < 4; ++q)
        *(f4v*)&arow[(q * 256 + tid) << 2] = z;
    __syncthreads();
    int j = i + tid - 255;
    if (j >= 0 && j < NN) {
        arow[j] = p0;
        bandT[(size_t)j * 768 + (i - (j & ~7) + 384)] = f2b(p0);
    }
    j = i + tid + 1;
    if (tid < 255 && j >= 0 && j < NN) {
        arow[j] = p1;
        bandT[(size_t)j * 768 + (i - (j & ~7) + 384)] = f2b(p1);
    }
}

// ---------------- y1 = att^T @ V via MFMA, direct-global operands -----------
__global__ __launch_bounds__(256, 2)
void attT_v_mfma(const short* __restrict__ bandT, const short* __restrict__ Vt,
                 short* __restrict__ y1b)
{
    const int t = threadIdx.x, l = t & 63, w = t >> 6;
    const int wm = w >> 1, wn = w & 1;
    const int lr = l & 15, lk = (l >> 4) << 3;
    const int r0 = blockIdx.y << 7;
    const int n0 = blockIdx.x << 6;

    f32x4 acc[4][2] = {};
    for (int ks = 0; ks < 20; ++ks) {
        const int j0 = r0 - 256 + (ks << 5);
        if (j0 < 0 || j0 >= NN) continue;
        bf16x8 b[2];
        #pragma unroll
        for (int j = 0; j < 2; ++j)
            b[j] = *(const bf16x8*)&Vt[(size_t)(n0 + wn * 32 + j * 16 + lr) * NN + j0 + lk];
        #pragma unroll
        for (int i = 0; i < 4; ++i) {
            const int r = r0 + wm * 64 + i * 16 + lr;
            const int cc = j0 + lk - (r & ~7) + 384;
            bf16x8 a = *(const bf16x8*)&bandT[(size_t)r * 768 + cc];
            #pragma unroll
            for (int j = 0; j < 2; ++j)
                acc[i][j] = __builtin_amdgcn_mfma_f32_16x16x32_bf16(a, b[j], acc[i][j], 0, 0, 0);
        }
    }
    const int rb = (l >> 4) << 2;
    #pragma unroll
    for (int i = 0; i < 4; ++i)
        #pragma unroll
        for (int j = 0; j < 2; ++j)
            #pragma unroll
            for (int r = 0; r < 4; ++r)
                y1b[(size_t)(r0 + wm * 64 + i * 16 + rb + r) * MM + n0 + wn * 32 + j * 16 + lr]
                    = f2b(acc[i][j][r]);
}

extern "C" void kernel_launch(void* const* d_in, const int* in_sizes, int n_in,
                              void* d_out, int out_size, void* d_ws, size_t ws_size,
                              hipStream_t stream)
{
    const float* x    = (const float*)d_in[0];
    const float* Wq   = (const float*)d_in[1];
    const float* Wk   = (const float*)d_in[2];
    const float* Wv   = (const float*)d_in[3];
    const float* Wofx = (const float*)d_in[4];
    const float* bofx = (const float*)d_in[5];
    const float* Wofy = (const float*)d_in[6];
    const float* bofy = (const float*)d_in[7];
    const float* Wout = (const float*)d_in[8];

    float* y_out   = (float*)d_out;
    float* att_out = (float*)d_out + (size_t)NN * MM;

    char* wsb = (char*)d_ws;
    const size_t MB = 1024 * 1024;
    // Liveness-verified layout. Sizes: xh/xl/Qh/Ql/xnb/y1b 8 MB; ofxyh/ofxyl
    // 16 MB; pairs 16 MB (u32!); WqT/WofxyT 4 MB each half; WkvT 4 MB;
    // WoutT 2 MB; Kb 8 MB; Vtb 8 MB; band 8 MB; bandT 6 MB. Peak 64 MB:
    //  split_x:     -> xh[16,24) xl[24,32)
    //  trsplit Wq:  -> WqTh[32,34) WqTl[34,36)
    //  Q-GEMM:      reads xh xl WqT -> Qh[0,8) Ql[8,16)      (xh,xl,WqT dead)
    //  trsplit ofxy:-> WofxyTh[16,20) WofxyTl[20,24)  (over xh, dead)
    //  ofxy-GEMM:   reads Qh Ql WofxyT -> ofxyh[32,48) ofxyl[48,64)
    //               (Ql, WofxyT dead)
    //  build_pairs: reads x -> pairs[16,32)   (over WofxyT+xl, dead)
    //  grid_sample: reads pairs[16,32) ofxyh[32,48) ofxyl[48,64)
    //               -> xnb[8,16) (over Ql, dead); Qh[0,8) LIVE: 64 MB exactly
    //  transposes:  -> WkvT[16,20) WoutT[20,22)  (over pairs, dead)
    //  KV-GEMM:     reads xnb WkvT -> Kb[24,32) Vtb[32,40)   (xnb, WkvT dead)
    //  logits:      reads Qh Kb -> band[40,48)               (Qh dead after)
    //  softmax:     reads band -> att_out, bandT[48,54)      (band dead)
    //  attT_v:      reads bandT Vtb -> y1b[8,16)  (over xnb, dead)
    //  final:       reads y1b WoutT[20,22) -> y_out
    short*    Qh      = (short*)(wsb + 0);
    short*    Ql      = (short*)(wsb + 8 * MB);
    short*    xh      = (short*)(wsb + 16 * MB);
    short*    xl      = (short*)(wsb + 24 * MB);
    short*    WqTh    = (short*)(wsb + 32 * MB);
    short*    WqTl    = (short*)(wsb + 34 * MB);
    short*    WofxyTh = (short*)(wsb + 16 * MB);   // over xh (dead)
    short*    WofxyTl = (short*)(wsb + 20 * MB);
    short*    ofxyh   = (short*)(wsb + 32 * MB);   // over WqT (dead)
    short*    ofxyl   = (short*)(wsb + 48 * MB);
    unsigned* pairs   = (unsigned*)(wsb + 16 * MB);// over WofxyT+xl (dead), 16 MB
    short*    xnb     = (short*)(wsb + 8 * MB);    // over Ql (dead)
    short*    WkvT    = (short*)(wsb + 16 * MB);   // over pairs (dead)
    short*    WoutT   = (short*)(wsb + 20 * MB);
    short*    Kb      = (short*)(wsb + 24 * MB);   // over pairs tail (dead)
    short*    Vtb     = (short*)(wsb + 32 * MB);   // over ofxyh (dead)
    float*    band    = (float*)(wsb + 40 * MB);   // over ofxyh tail (dead)
    short*    bandT   = (short*)(wsb + 48 * MB);   // over ofxyl (dead)
    short*    y1b     = (short*)(wsb + 8 * MB);    // over xnb (dead)

    const dim3 blk(256);
    const dim3 tgrid(32, 32), tblk(32, 8);

    // ---- sensitive path via split-bf16 MFMA ----
    split_x_k<<<dim3(4096), blk, 0, stream>>>(x, xh, xl);
    trsplit_k<<<tgrid, tblk, 0, stream>>>(Wq, WqTh, WqTl);
    gemm_split<false><<<dim3(8, 32), blk, 0, stream>>>(
        xh, xl, WqTh, WqTl, nullptr, nullptr, Qh, Ql, 1024);
    trsplit_k<<<tgrid, tblk, 0, stream>>>(Wofx, WofxyTh, WofxyTl);
    trsplit_k<<<tgrid, tblk, 0, stream>>>(Wofy, WofxyTh + 1024 * 1024, WofxyTl + 1024 * 1024);
    gemm_split<true><<<dim3(16, 32), blk, 0, stream>>>(
        Qh, Ql, WofxyTh, WofxyTl, bofx, bofy, ofxyh, ofxyl, 2048);

    // pair table + gather (2 u32 loads per output)
    build_pairs_k<<<dim3(NN), blk, 0, stream>>>(x, pairs);
    grid_sample_k<<<dim3(NN), blk, 0, stream>>>(pairs, ofxyh, ofxyl, xnb);

    // ---- bf16 path ----
    transpose_f32_bf16<<<tgrid, tblk, 0, stream>>>(Wk, WkvT);
    transpose_f32_bf16<<<tgrid, tblk, 0, stream>>>(Wv, WkvT + 1024 * 1024);
    transpose_f32_bf16<<<tgrid, tblk, 0, stream>>>(Wout, WoutT);

    // K | Vt fused
    mfma_gemm<4><<<dim3(16, 32), blk, 0, stream>>>(xnb, WkvT, Kb, Vtb);
    // banded logits
    mfma_gemm<3><<<dim3(5, 32), blk, 0, stream>>>(Qh, Kb, band, nullptr);
    // softmax -> att rows in d_out + bandT bf16 scatter
    hipMemsetAsync(bandT, 0, (size_t)NN * 768 * sizeof(short), stream);
    band_softmax<<<dim3(NN), blk, 0, stream>>>(band, att_out, bandT);
    // y1 = att^T @ V
    attT_v_mfma<<<dim3(16, 32), blk, 0, stream>>>(bandT, Vtb, y1b);
    // y = y1 @ Wout
    mfma_gemm<2><<<dim3(8, 32), blk, 0, stream>>>(y1b, WoutT, y_out, nullptr);
}